// Round 13
// baseline (663.303 us; speedup 1.0000x reference)
//
#include <hip/hip_runtime.h>
#include <hip/hip_cooperative_groups.h>

namespace cg = cooperative_groups;

#define N_NODES 100000
#define N_EDGES 1600000
#define NBUCK 391            // ceil(N_NODES/256) buckets of 256 nodes
#define SCAT_GRID 512
#define SCAT_CH 3125         // SCAT_GRID * SCAT_CH == N_EDGES

typedef short bf16x8 __attribute__((ext_vector_type(8)));
typedef float f32x4 __attribute__((ext_vector_type(4)));

#define GLOBAL_AS __attribute__((address_space(1)))
#define LDS_AS __attribute__((address_space(3)))

// ---- bf16 helpers (RNE) ----------------------------------------------------
__device__ __forceinline__ unsigned short f2b(float x) {
  unsigned int u = __float_as_uint(x);
  u = (u + 0x7FFFu + ((u >> 16) & 1u)) >> 16;
  return (unsigned short)u;
}
__device__ __forceinline__ unsigned int pack2(float lo, float hi) {
  return ((unsigned int)f2b(hi) << 16) | (unsigned int)f2b(lo);
}

// ---------------------------------------------------------------------------
// ONE cooperative kernel: zero + weight-cvt | hist + x-cvt | scan | scatter |
// per-bucket node sort.  512 blocks x 256 threads (2/CU, co-resident).
// ---------------------------------------------------------------------------
__global__ __launch_bounds__(256) void build_all(
    const int* __restrict__ src, const int* __restrict__ dst,
    const float* __restrict__ ew, const float4* __restrict__ x4,
    const float* __restrict__ W1, const float* __restrict__ W2,
    const float* __restrict__ W3,
    int* __restrict__ bucket_start, int* __restrict__ cursorA,
    int* __restrict__ start, uint2* __restrict__ edgesA,
    uint2* __restrict__ edges, uint4* __restrict__ xb,
    unsigned short* __restrict__ Wb1, unsigned short* __restrict__ Wb2,
    unsigned short* __restrict__ Wb3) {
  cg::grid_group grid = cg::this_grid();
  __shared__ int hist[NBUCK];
  __shared__ int base[NBUCK];
  __shared__ int lcur[NBUCK];
  __shared__ int s[256];
  const int t = threadIdx.x;
  const int b = blockIdx.x;
  const int gtid = b * 256 + t;

  // ---- Phase 0: zero bucket counters; convert weights (131072 elems = grid)
  if (b == 0)
    for (int i = t; i <= NBUCK; i += 256) bucket_start[i] = 0;
  if (gtid < 32768) {
    const int n = gtid >> 7, k = gtid & 127;
    Wb1[n * 128 + k] = f2b(W1[k * 256 + n]);
  } else if (gtid < 98304) {
    const int o = gtid - 32768, n = o >> 8, k = o & 255;
    Wb2[n * 256 + k] = f2b(W2[k * 256 + n]);
  } else {
    const int o = gtid - 98304, n = o >> 8, k = o & 255;
    Wb3[n * 256 + k] = f2b(W3[k * 128 + n]);
  }
  grid.sync();

  // ---- Phase 1: bucket histogram, with x->bf16 conversion interleaved
  {
    for (int i = t; i < NBUCK; i += 256) hist[i] = 0;
    __syncthreads();
    const int e0 = b * SCAT_CH, e1 = min(e0 + SCAT_CH, N_EDGES);
    for (int i = e0 + t; i < e1; i += 256) atomicAdd(&hist[dst[i] >> 8], 1);
    // streaming conversion hides under atomic latency
    for (int i = gtid; i < N_NODES * 128 / 8; i += SCAT_GRID * 256) {
      const float4 a = x4[2 * i], c = x4[2 * i + 1];
      uint4 o;
      o.x = pack2(a.x, a.y); o.y = pack2(a.z, a.w);
      o.z = pack2(c.x, c.y); o.w = pack2(c.z, c.w);
      xb[i] = o;
    }
    __syncthreads();
    for (int i = t; i < NBUCK; i += 256)
      if (hist[i]) atomicAdd(&bucket_start[i], hist[i]);
  }
  grid.sync();

  // ---- Phase 2: exclusive scan of 391 bucket totals (block 0, pair-Hillis)
  if (b == 0) {
    const int i0 = 2 * t, i1 = 2 * t + 1;
    const int a0 = (i0 < NBUCK) ? bucket_start[i0] : 0;
    const int a1 = (i1 < NBUCK) ? bucket_start[i1] : 0;
    const int ps = a0 + a1;
    s[t] = ps;
    __syncthreads();
    for (int off = 1; off < 256; off <<= 1) {
      const int v = (t >= off) ? s[t - off] : 0;
      __syncthreads();
      s[t] += v;
      __syncthreads();
    }
    const int excl = s[t] - ps;
    if (i0 < NBUCK) { bucket_start[i0] = excl;      cursorA[i0] = excl; }
    if (i1 < NBUCK) { bucket_start[i1] = excl + a0; cursorA[i1] = excl + a0; }
    if (t == 0) bucket_start[NBUCK] = N_EDGES;
  }
  grid.sync();

  // ---- Phase 3: chunked counting scatter into bucket regions
  {
    for (int i = t; i < NBUCK; i += 256) { hist[i] = 0; lcur[i] = 0; }
    __syncthreads();
    const int e0 = b * SCAT_CH, e1 = min(e0 + SCAT_CH, N_EDGES);
    for (int i = e0 + t; i < e1; i += 256) atomicAdd(&hist[dst[i] >> 8], 1);
    __syncthreads();
    for (int i = t; i < NBUCK; i += 256) {
      const int h = hist[i];
      base[i] = h ? atomicAdd(&cursorA[i], h) : 0;
    }
    __syncthreads();
    for (int i = e0 + t; i < e1; i += 256) {
      const int d = dst[i];
      const int bb = d >> 8;
      const int pos = base[bb] + atomicAdd(&lcur[bb], 1);
      uint2 e;
      e.x = (unsigned int)src[i] | ((unsigned int)(d & 255) << 17);
      e.y = __float_as_uint(ew[i]);
      edgesA[pos] = e;
    }
  }
  grid.sync();

  // ---- Phase 4: per-bucket node sort (blocks 0..NBUCK-1)
  if (b < NBUCK) {
    const int n0 = b * 256;
    const int r0 = bucket_start[b];
    const int r1 = bucket_start[b + 1];
    hist[t] = 0;
    __syncthreads();
    for (int i = r0 + t; i < r1; i += 256)
      atomicAdd(&hist[edgesA[i].x >> 17], 1);
    __syncthreads();
    const int v = hist[t];
    s[t] = v;
    __syncthreads();
    for (int off = 1; off < 256; off <<= 1) {
      const int xv = (t >= off) ? s[t - off] : 0;
      __syncthreads();
      s[t] += xv;
      __syncthreads();
    }
    const int nodeStart = r0 + s[t] - v;      // exclusive within bucket
    lcur[t] = nodeStart;
    if (n0 + t < N_NODES) start[n0 + t] = nodeStart;
    if (b == 0 && t == 0) start[N_NODES] = N_EDGES;
    __syncthreads();
    for (int i = r0 + t; i < r1; i += 256) {
      const uint2 e = edgesA[i];
      const int j = e.x >> 17;
      const int pos = atomicAdd(&lcur[j], 1);
      uint2 o;
      o.x = e.x & 0x1FFFFu;
      o.y = e.y;
      edges[pos] = o;
    }
  }
}

// ---------------------------------------------------------------------------
// out[n,:] = sum_e w_e * sup[src_e,:]  — sup bf16, fp32 accumulate.
// 8 edges in flight per group for memory-level parallelism.
// ---------------------------------------------------------------------------
__device__ __forceinline__ void acc8(float* acc, uint4 v, float w) {
  const unsigned int u[4] = {v.x, v.y, v.z, v.w};
#pragma unroll
  for (int q = 0; q < 4; ++q) {
    acc[2 * q]     += w * __uint_as_float(u[q] << 16);
    acc[2 * q + 1] += w * __uint_as_float(u[q] & 0xFFFF0000u);
  }
}

template <int D, bool F32OUT>
__global__ __launch_bounds__(256) void aggregate_k(
    const uint4* __restrict__ sup, const int* __restrict__ start,
    const uint2* __restrict__ edges, void* __restrict__ outv,
    const float* __restrict__ bias) {
  constexpr int L = D / 8;          // lanes per node, 16B (8 bf16) per lane
  constexpr int GPB = 256 / L;
  const int lane = threadIdx.x % L;
  const int grp  = threadIdx.x / L;
  const int n = blockIdx.x * GPB + grp;
  if (n >= N_NODES) return;

  float acc[8] = {0.f, 0.f, 0.f, 0.f, 0.f, 0.f, 0.f, 0.f};
  const int s0 = start[n];
  const int s1 = start[n + 1];
  int i = s0;
  for (; i + 8 <= s1; i += 8) {
    uint2 e[8];
#pragma unroll
    for (int q = 0; q < 8; ++q) e[q] = edges[i + q];
    uint4 v[8];
#pragma unroll
    for (int q = 0; q < 8; ++q) v[q] = sup[(size_t)e[q].x * L + lane];
#pragma unroll
    for (int q = 0; q < 8; ++q) acc8(acc, v[q], __uint_as_float(e[q].y));
  }
  for (; i + 4 <= s1; i += 4) {
    const uint2 e0 = edges[i], e1 = edges[i + 1];
    const uint2 e2 = edges[i + 2], e3 = edges[i + 3];
    const uint4 v0 = sup[(size_t)e0.x * L + lane];
    const uint4 v1 = sup[(size_t)e1.x * L + lane];
    const uint4 v2 = sup[(size_t)e2.x * L + lane];
    const uint4 v3 = sup[(size_t)e3.x * L + lane];
    acc8(acc, v0, __uint_as_float(e0.y));
    acc8(acc, v1, __uint_as_float(e1.y));
    acc8(acc, v2, __uint_as_float(e2.y));
    acc8(acc, v3, __uint_as_float(e3.y));
  }
  for (; i < s1; ++i) {
    const uint2 e = edges[i];
    const uint4 v = sup[(size_t)e.x * L + lane];
    acc8(acc, v, __uint_as_float(e.y));
  }

  if (F32OUT) {
    float4* o = (float4*)outv + (size_t)n * (D / 4) + lane * 2;
    const float* bj = bias + lane * 8;
    float4 f0 = {acc[0] + bj[0], acc[1] + bj[1], acc[2] + bj[2], acc[3] + bj[3]};
    float4 f1 = {acc[4] + bj[4], acc[5] + bj[5], acc[6] + bj[6], acc[7] + bj[7]};
    o[0] = f0;
    o[1] = f1;
  } else {
    uint4 o;
    o.x = pack2(acc[0], acc[1]);
    o.y = pack2(acc[2], acc[3]);
    o.z = pack2(acc[4], acc[5]);
    o.w = pack2(acc[6], acc[7]);
    ((uint4*)outv)[(size_t)n * L + lane] = o;
  }
}

// ---------------------------------------------------------------------------
// Stage a [128 rows][64 k] bf16 tile into LDS via global_load_lds (16B/lane).
// Linear LDS dest + XOR-swizzled GLOBAL source column; same XOR on ds_read.
// ---------------------------------------------------------------------------
template <int LD>
__device__ __forceinline__ void stage_tile(
    const unsigned short* __restrict__ gbase,  // element [row0][k0]
    unsigned short* lds, int tid) {
  const int wid = tid >> 6, lane = tid & 63;
#pragma unroll
  for (int i = 0; i < 4; ++i) {
    const int chunk = i * 256 + wid * 64 + lane;   // 16B chunk index
    const int r = chunk >> 3;
    const int c8 = chunk & 7;
    const int c8s = c8 ^ (r & 7);
    const unsigned short* src = gbase + (size_t)r * LD + c8s * 8;
    unsigned short* dstbase = lds + (size_t)(i * 256 + wid * 64) * 8;  // wave-uniform
    __builtin_amdgcn_global_load_lds((GLOBAL_AS void*)src,
                                     (LDS_AS void*)dstbase, 16, 0, 0);
  }
}

// ---------------------------------------------------------------------------
// C[N,M](bf16) = X[N,K](bf16) @ Wb[M,K](bf16, pre-transposed) (+bias, ReLU).
// 128x128 tile, BK=64, double-buffered LDS, global_load_lds staging,
// XOR-swizzled reads. Flattened grid, bn fastest, bijective XCD swizzle.
// mfma_f32_16x16x32_bf16; C/D: col=lane&15, row=(lane>>4)*4+reg.
// ---------------------------------------------------------------------------
template <int K, int NBN, bool BIAS_RELU>
__global__ __launch_bounds__(256) void gemm_mfma(
    const unsigned short* __restrict__ X, const unsigned short* __restrict__ Wb,
    const float* __restrict__ bias, unsigned short* __restrict__ C, int M) {
  __shared__ unsigned short As[2][128 * 64];
  __shared__ unsigned short Bs[2][128 * 64];
  const int tid = threadIdx.x;

  const int nwg = gridDim.x;
  const int q = nwg >> 3, r8 = nwg & 7;
  const int xcd = blockIdx.x & 7, loc = blockIdx.x >> 3;
  const int wgid = (xcd < r8 ? xcd * (q + 1) : r8 * (q + 1) + (xcd - r8) * q) + loc;
  const int bm = (wgid / NBN) * 128;
  const int bn = (wgid % NBN) * 128;
  constexpr int NT = K / 64;

  const int wid  = tid >> 6;
  const int wm   = wid >> 1;
  const int wn   = wid & 1;
  const int lane = tid & 63;
  const int lrow = lane & 15;
  const int lsel = lane >> 4;

  stage_tile<K>(X + (size_t)bm * K, As[0], tid);
  stage_tile<K>(Wb + (size_t)bn * K, Bs[0], tid);
  __syncthreads();

  f32x4 acc[4][4];
#pragma unroll
  for (int m = 0; m < 4; ++m)
#pragma unroll
    for (int n = 0; n < 4; ++n) {
      acc[m][n].x = 0.f; acc[m][n].y = 0.f; acc[m][n].z = 0.f; acc[m][n].w = 0.f;
    }

  int cur = 0;
  for (int t = 0; t < NT; ++t) {
    if (t + 1 < NT) {
      stage_tile<K>(X + (size_t)bm * K + (t + 1) * 64, As[cur ^ 1], tid);
      stage_tile<K>(Wb + (size_t)bn * K + (t + 1) * 64, Bs[cur ^ 1], tid);
    }
#pragma unroll
    for (int ks = 0; ks < 2; ++ks) {
      bf16x8 a[4], b[4];
#pragma unroll
      for (int m = 0; m < 4; ++m) {
        const int r = wm * 64 + m * 16 + lrow;
        const int cc = ks * 4 + lsel;
        a[m] = *reinterpret_cast<const bf16x8*>(
            &As[cur][r * 64 + (cc ^ (r & 7)) * 8]);
      }
#pragma unroll
      for (int n = 0; n < 4; ++n) {
        const int r = wn * 64 + n * 16 + lrow;
        const int cc = ks * 4 + lsel;
        b[n] = *reinterpret_cast<const bf16x8*>(
            &Bs[cur][r * 64 + (cc ^ (r & 7)) * 8]);
      }
#pragma unroll
      for (int m = 0; m < 4; ++m)
#pragma unroll
        for (int n = 0; n < 4; ++n)
          acc[m][n] = __builtin_amdgcn_mfma_f32_16x16x32_bf16(a[m], b[n],
                                                              acc[m][n], 0, 0, 0);
    }
    __syncthreads();
    cur ^= 1;
  }

#pragma unroll
  for (int n = 0; n < 4; ++n) {
    const int gcol = bn + wn * 64 + n * 16 + lrow;
    const float bv = BIAS_RELU ? bias[gcol] : 0.f;
#pragma unroll
    for (int m = 0; m < 4; ++m) {
      const int gmBase = bm + wm * 64 + m * 16 + lsel * 4;
#pragma unroll
      for (int j = 0; j < 4; ++j) {
        const int gm = gmBase + j;
        if (gm < N_NODES) {
          float v = acc[m][n][j] + bv;
          if (BIAS_RELU) v = fmaxf(v, 0.f);
          C[(size_t)gm * M + gcol] = f2b(v);
        }
      }
    }
  }
}

// ---------------------------------------------------------------------------
extern "C" void kernel_launch(void* const* d_in, const int* in_sizes, int n_in,
                              void* d_out, int out_size, void* d_ws,
                              size_t ws_size, hipStream_t stream) {
  const int*   src = (const int*)d_in[1];
  const int*   dst = (const int*)d_in[2];
  const float* ew  = (const float*)d_in[3];
  const float4* x4 = (const float4*)d_in[0];
  const float* W1  = (const float*)d_in[4];
  const float* b1  = (const float*)d_in[5];
  const float* W2  = (const float*)d_in[6];
  const float* b2  = (const float*)d_in[7];
  const float* W3  = (const float*)d_in[8];
  const float* b3  = (const float*)d_in[9];

  // ws layout: two bf16 activation buffers (51.2 MB each) + CSR + Wb
  unsigned short* buf0 = (unsigned short*)d_ws;
  unsigned short* buf1 = buf0 + (size_t)N_NODES * 256;
  int* csr = (int*)((char*)d_ws + 102400000);           // 16B-aligned
  int*   start        = csr;                            // @0      (100001)
  int*   bucket_start = csr + 100004;                   // @100004 (392)
  int*   cursorA      = csr + 100400;                   // @100400 (391)
  uint2* edges        = (uint2*)(csr + 100800);         // 16B-aligned, 12.8MB
  unsigned short* Wb1 = (unsigned short*)(edges + N_EDGES);  // [256][128]
  unsigned short* Wb2 = Wb1 + 256 * 128;                     // [256][256]
  unsigned short* Wb3 = Wb2 + 256 * 256;                     // [128][256]
  uint2* edgesA = (uint2*)buf1;   // pass-A staging (dead before layer-1 out)
  uint4* xb     = (uint4*)buf0;

  // ---- fused CSR build + conversions (one cooperative dispatch)
  {
    void* args[] = {
        (void*)&src, (void*)&dst, (void*)&ew, (void*)&x4,
        (void*)&W1, (void*)&W2, (void*)&W3,
        (void*)&bucket_start, (void*)&cursorA, (void*)&start,
        (void*)&edgesA, (void*)&edges, (void*)&xb,
        (void*)&Wb1, (void*)&Wb2, (void*)&Wb3};
    hipLaunchCooperativeKernel((void*)build_all, dim3(SCAT_GRID), dim3(256),
                               args, 0, stream);
  }

  // ---- Layer 1: h1 = relu((A xb) W1 + b1)
  aggregate_k<128, false><<<6250, 256, 0, stream>>>(
      (const uint4*)buf0, start, edges, buf1, nullptr);
  gemm_mfma<128, 2, true><<<1564, 256, 0, stream>>>(buf1, Wb1, b1, buf0, 256);

  // ---- Layer 2: h2 = relu((A h1) W2 + b2)
  aggregate_k<256, false><<<12500, 256, 0, stream>>>(
      (const uint4*)buf0, start, edges, buf1, nullptr);
  gemm_mfma<256, 2, true><<<1564, 256, 0, stream>>>(buf1, Wb2, b2, buf0, 256);

  // ---- Layer 3: out = A (h2 W3) + b3   (aggregate at D=128, bias in epilogue)
  gemm_mfma<256, 1, false><<<782, 256, 0, stream>>>(buf0, Wb3, nullptr, buf1, 128);
  aggregate_k<128, true><<<6250, 256, 0, stream>>>(
      (const uint4*)buf1, start, edges, d_out, b3);
}

// Round 14
// 442.843 us; speedup vs baseline: 1.4978x; 1.4978x over previous
//
#include <hip/hip_runtime.h>

#define N_NODES 100000
#define N_EDGES 1600000
#define NBUCK 391            // ceil(N_NODES/256) buckets of 256 nodes
#define SCAT_GRID 512
#define SCAT_CH 3125         // SCAT_GRID * SCAT_CH == N_EDGES

typedef short bf16x8 __attribute__((ext_vector_type(8)));
typedef float f32x4 __attribute__((ext_vector_type(4)));

#define GLOBAL_AS __attribute__((address_space(1)))
#define LDS_AS __attribute__((address_space(3)))

// ---- bf16 helpers (RNE) ----------------------------------------------------
__device__ __forceinline__ unsigned short f2b(float x) {
  unsigned int u = __float_as_uint(x);
  u = (u + 0x7FFFu + ((u >> 16) & 1u)) >> 16;
  return (unsigned short)u;
}
__device__ __forceinline__ unsigned int pack2(float lo, float hi) {
  return ((unsigned int)f2b(hi) << 16) | (unsigned int)f2b(lo);
}

// ---------------------------------------------------------------------------
__global__ void zero_i32(int* __restrict__ p, int n) {
  int i = blockIdx.x * blockDim.x + threadIdx.x;
  const int stride = gridDim.x * blockDim.x;
  for (; i < n; i += stride) p[i] = 0;
}

// ---------------------------------------------------------------------------
// bucket-level histogram: LDS hist per chunk
// ---------------------------------------------------------------------------
__global__ __launch_bounds__(256) void bucket_hist(const int* __restrict__ dst,
                                                   int* __restrict__ btot) {
  __shared__ int h[NBUCK];
  const int t = threadIdx.x;
  const int e0 = blockIdx.x * SCAT_CH;
  const int e1 = min(e0 + SCAT_CH, N_EDGES);
  for (int i = t; i < NBUCK; i += 256) h[i] = 0;
  __syncthreads();
  for (int i = e0 + t; i < e1; i += 256) atomicAdd(&h[dst[i] >> 8], 1);
  __syncthreads();
  for (int i = t; i < NBUCK; i += 256)
    if (h[i]) atomicAdd(&btot[i], h[i]);
}

// ---- single tiny scan over 391 bucket totals (in place) -------------------
__global__ __launch_bounds__(512) void scan_buckets(int* __restrict__ bs,
                                                    int* __restrict__ cursorA) {
  __shared__ int s[512];
  const int t = threadIdx.x;
  const int v = (t < NBUCK) ? bs[t] : 0;
  s[t] = v;
  __syncthreads();
  for (int off = 1; off < 512; off <<= 1) {
    int x = (t >= off) ? s[t - off] : 0;
    __syncthreads();
    s[t] += x;
    __syncthreads();
  }
  const int excl = s[t] - v;
  if (t < NBUCK) {
    bs[t] = excl;
    cursorA[t] = excl;
  }
  if (t == 0) bs[NBUCK] = N_EDGES;
}

// ---------------------------------------------------------------------------
// Pass A: chunked counting scatter into 256-node bucket regions.
// Packs (src | (dst&255)<<17, w).
// ---------------------------------------------------------------------------
__global__ __launch_bounds__(256) void bucket_scatter(
    const int* __restrict__ src, const int* __restrict__ dst,
    const float* __restrict__ ew, int* __restrict__ cursorA,
    uint2* __restrict__ edgesA) {
  __shared__ int hist[NBUCK];
  __shared__ int base[NBUCK];
  __shared__ int lcur[NBUCK];
  const int t = threadIdx.x;
  const int e0 = blockIdx.x * SCAT_CH;
  const int e1 = min(e0 + SCAT_CH, N_EDGES);

  for (int i = t; i < NBUCK; i += 256) { hist[i] = 0; lcur[i] = 0; }
  __syncthreads();
  for (int i = e0 + t; i < e1; i += 256) atomicAdd(&hist[dst[i] >> 8], 1);
  __syncthreads();
  for (int i = t; i < NBUCK; i += 256) {
    const int h = hist[i];
    base[i] = h ? atomicAdd(&cursorA[i], h) : 0;
  }
  __syncthreads();
  for (int i = e0 + t; i < e1; i += 256) {
    const int d = dst[i];
    const int b = d >> 8;
    const int pos = base[b] + atomicAdd(&lcur[b], 1);
    uint2 e;
    e.x = (unsigned int)src[i] | ((unsigned int)(d & 255) << 17);
    e.y = __float_as_uint(ew[i]);
    edgesA[pos] = e;
  }
}

// ---------------------------------------------------------------------------
// Pass B: one block per bucket, 512 threads. Computes node degrees (LDS) +
// local scan -> writes start[] AND node-sorts its region.
// ---------------------------------------------------------------------------
__global__ __launch_bounds__(512) void bucket_sort(
    const uint2* __restrict__ edgesA, const int* __restrict__ bucket_start,
    int* __restrict__ start, uint2* __restrict__ edges) {
  __shared__ int cnt[256];
  __shared__ int scn[256];
  __shared__ int cur[256];
  const int b = blockIdx.x;
  const int n0 = b * 256;
  const int t = threadIdx.x;
  const int r0 = bucket_start[b];
  const int r1 = bucket_start[b + 1];

  if (t < 256) cnt[t] = 0;
  __syncthreads();
  for (int i = r0 + t; i < r1; i += 512)
    atomicAdd(&cnt[edgesA[i].x >> 17], 1);
  __syncthreads();
  const int v = (t < 256) ? cnt[t] : 0;
  if (t < 256) scn[t] = v;
  __syncthreads();
  for (int off = 1; off < 256; off <<= 1) {
    int x = (t >= off && t < 256) ? scn[t - off] : 0;
    __syncthreads();
    if (t < 256) scn[t] += x;
    __syncthreads();
  }
  if (t < 256) {
    const int nodeStart = r0 + scn[t] - v;     // exclusive within bucket
    cur[t] = nodeStart;
    if (n0 + t < N_NODES) start[n0 + t] = nodeStart;
  }
  if (b == 0 && t == 0) start[N_NODES] = N_EDGES;
  __syncthreads();
  for (int i = r0 + t; i < r1; i += 512) {
    const uint2 e = edgesA[i];
    const int j = e.x >> 17;
    const int pos = atomicAdd(&cur[j], 1);
    uint2 o;
    o.x = e.x & 0x1FFFFu;
    o.y = e.y;
    edges[pos] = o;
  }
}

// ---- fp32 -> bf16 conversion (8 elems / thread) ---------------------------
__global__ void cvt_f32_bf16(const float4* __restrict__ in,
                             uint4* __restrict__ out, int n8) {
  const int i = blockIdx.x * blockDim.x + threadIdx.x;
  if (i >= n8) return;
  const float4 a = in[2 * i], b = in[2 * i + 1];
  uint4 o;
  o.x = pack2(a.x, a.y);
  o.y = pack2(a.z, a.w);
  o.z = pack2(b.x, b.y);
  o.w = pack2(b.z, b.w);
  out[i] = o;
}

// ---- all 3 weight matrices: W[k][n] fp32 -> Wb[n][k] bf16 in one launch ---
__global__ void cvt_w_all(const float* __restrict__ W1, const float* __restrict__ W2,
                          const float* __restrict__ W3,
                          unsigned short* __restrict__ Wb1,
                          unsigned short* __restrict__ Wb2,
                          unsigned short* __restrict__ Wb3) {
  const int b = blockIdx.x;
  const float* W; unsigned short* Wb; int K, M, n;
  if (b < 256)      { W = W1; Wb = Wb1; K = 128; M = 256; n = b; }
  else if (b < 512) { W = W2; Wb = Wb2; K = 256; M = 256; n = b - 256; }
  else              { W = W3; Wb = Wb3; K = 256; M = 128; n = b - 512; }
  for (int k = threadIdx.x; k < K; k += blockDim.x)
    Wb[(size_t)n * K + k] = f2b(W[(size_t)k * M + n]);
}

// ---------------------------------------------------------------------------
// out[n,:] = sum_e w_e * sup[src_e,:]  — sup bf16, fp32 accumulate.
// 8 edges in flight per group for memory-level parallelism.
// ---------------------------------------------------------------------------
__device__ __forceinline__ void acc8(float* acc, uint4 v, float w) {
  const unsigned int u[4] = {v.x, v.y, v.z, v.w};
#pragma unroll
  for (int q = 0; q < 4; ++q) {
    acc[2 * q]     += w * __uint_as_float(u[q] << 16);
    acc[2 * q + 1] += w * __uint_as_float(u[q] & 0xFFFF0000u);
  }
}

template <int D, bool F32OUT>
__global__ __launch_bounds__(256) void aggregate_k(
    const uint4* __restrict__ sup, const int* __restrict__ start,
    const uint2* __restrict__ edges, void* __restrict__ outv,
    const float* __restrict__ bias) {
  constexpr int L = D / 8;          // lanes per node, 16B (8 bf16) per lane
  constexpr int GPB = 256 / L;
  const int lane = threadIdx.x % L;
  const int grp  = threadIdx.x / L;
  const int n = blockIdx.x * GPB + grp;
  if (n >= N_NODES) return;

  float acc[8] = {0.f, 0.f, 0.f, 0.f, 0.f, 0.f, 0.f, 0.f};
  const int s0 = start[n];
  const int s1 = start[n + 1];
  int i = s0;
  for (; i + 8 <= s1; i += 8) {
    uint2 e[8];
#pragma unroll
    for (int q = 0; q < 8; ++q) e[q] = edges[i + q];
    uint4 v[8];
#pragma unroll
    for (int q = 0; q < 8; ++q) v[q] = sup[(size_t)e[q].x * L + lane];
#pragma unroll
    for (int q = 0; q < 8; ++q) acc8(acc, v[q], __uint_as_float(e[q].y));
  }
  for (; i + 4 <= s1; i += 4) {
    const uint2 e0 = edges[i], e1 = edges[i + 1];
    const uint2 e2 = edges[i + 2], e3 = edges[i + 3];
    const uint4 v0 = sup[(size_t)e0.x * L + lane];
    const uint4 v1 = sup[(size_t)e1.x * L + lane];
    const uint4 v2 = sup[(size_t)e2.x * L + lane];
    const uint4 v3 = sup[(size_t)e3.x * L + lane];
    acc8(acc, v0, __uint_as_float(e0.y));
    acc8(acc, v1, __uint_as_float(e1.y));
    acc8(acc, v2, __uint_as_float(e2.y));
    acc8(acc, v3, __uint_as_float(e3.y));
  }
  for (; i < s1; ++i) {
    const uint2 e = edges[i];
    const uint4 v = sup[(size_t)e.x * L + lane];
    acc8(acc, v, __uint_as_float(e.y));
  }

  if (F32OUT) {
    float4* o = (float4*)outv + (size_t)n * (D / 4) + lane * 2;
    const float* bj = bias + lane * 8;
    float4 f0 = {acc[0] + bj[0], acc[1] + bj[1], acc[2] + bj[2], acc[3] + bj[3]};
    float4 f1 = {acc[4] + bj[4], acc[5] + bj[5], acc[6] + bj[6], acc[7] + bj[7]};
    o[0] = f0;
    o[1] = f1;
  } else {
    uint4 o;
    o.x = pack2(acc[0], acc[1]);
    o.y = pack2(acc[2], acc[3]);
    o.z = pack2(acc[4], acc[5]);
    o.w = pack2(acc[6], acc[7]);
    ((uint4*)outv)[(size_t)n * L + lane] = o;
  }
}

// ---------------------------------------------------------------------------
// Stage a [128 rows][64 k] bf16 tile into LDS via global_load_lds (16B/lane).
// Linear LDS dest + XOR-swizzled GLOBAL source column; same XOR on ds_read.
// ---------------------------------------------------------------------------
template <int LD>
__device__ __forceinline__ void stage_tile(
    const unsigned short* __restrict__ gbase,  // element [row0][k0]
    unsigned short* lds, int tid) {
  const int wid = tid >> 6, lane = tid & 63;
#pragma unroll
  for (int i = 0; i < 4; ++i) {
    const int chunk = i * 256 + wid * 64 + lane;   // 16B chunk index
    const int r = chunk >> 3;
    const int c8 = chunk & 7;
    const int c8s = c8 ^ (r & 7);
    const unsigned short* src = gbase + (size_t)r * LD + c8s * 8;
    unsigned short* dstbase = lds + (size_t)(i * 256 + wid * 64) * 8;  // wave-uniform
    __builtin_amdgcn_global_load_lds((GLOBAL_AS void*)src,
                                     (LDS_AS void*)dstbase, 16, 0, 0);
  }
}

// ---------------------------------------------------------------------------
// C[N,M](bf16) = X[N,K](bf16) @ Wb[M,K](bf16, pre-transposed) (+bias, ReLU).
// 128x128 tile, BK=64, double-buffered LDS, global_load_lds staging,
// XOR-swizzled reads. Flattened grid, bn fastest, bijective XCD swizzle.
// mfma_f32_16x16x32_bf16; C/D: col=lane&15, row=(lane>>4)*4+reg.
// ---------------------------------------------------------------------------
template <int K, int NBN, bool BIAS_RELU>
__global__ __launch_bounds__(256) void gemm_mfma(
    const unsigned short* __restrict__ X, const unsigned short* __restrict__ Wb,
    const float* __restrict__ bias, unsigned short* __restrict__ C, int M) {
  __shared__ unsigned short As[2][128 * 64];
  __shared__ unsigned short Bs[2][128 * 64];
  const int tid = threadIdx.x;

  const int nwg = gridDim.x;
  const int q = nwg >> 3, r8 = nwg & 7;
  const int xcd = blockIdx.x & 7, loc = blockIdx.x >> 3;
  const int wgid = (xcd < r8 ? xcd * (q + 1) : r8 * (q + 1) + (xcd - r8) * q) + loc;
  const int bm = (wgid / NBN) * 128;
  const int bn = (wgid % NBN) * 128;
  constexpr int NT = K / 64;

  const int wid  = tid >> 6;
  const int wm   = wid >> 1;
  const int wn   = wid & 1;
  const int lane = tid & 63;
  const int lrow = lane & 15;
  const int lsel = lane >> 4;

  stage_tile<K>(X + (size_t)bm * K, As[0], tid);
  stage_tile<K>(Wb + (size_t)bn * K, Bs[0], tid);
  __syncthreads();

  f32x4 acc[4][4];
#pragma unroll
  for (int m = 0; m < 4; ++m)
#pragma unroll
    for (int n = 0; n < 4; ++n) {
      acc[m][n].x = 0.f; acc[m][n].y = 0.f; acc[m][n].z = 0.f; acc[m][n].w = 0.f;
    }

  int cur = 0;
  for (int t = 0; t < NT; ++t) {
    if (t + 1 < NT) {
      stage_tile<K>(X + (size_t)bm * K + (t + 1) * 64, As[cur ^ 1], tid);
      stage_tile<K>(Wb + (size_t)bn * K + (t + 1) * 64, Bs[cur ^ 1], tid);
    }
#pragma unroll
    for (int ks = 0; ks < 2; ++ks) {
      bf16x8 a[4], b[4];
#pragma unroll
      for (int m = 0; m < 4; ++m) {
        const int r = wm * 64 + m * 16 + lrow;
        const int cc = ks * 4 + lsel;
        a[m] = *reinterpret_cast<const bf16x8*>(
            &As[cur][r * 64 + (cc ^ (r & 7)) * 8]);
      }
#pragma unroll
      for (int n = 0; n < 4; ++n) {
        const int r = wn * 64 + n * 16 + lrow;
        const int cc = ks * 4 + lsel;
        b[n] = *reinterpret_cast<const bf16x8*>(
            &Bs[cur][r * 64 + (cc ^ (r & 7)) * 8]);
      }
#pragma unroll
      for (int m = 0; m < 4; ++m)
#pragma unroll
        for (int n = 0; n < 4; ++n)
          acc[m][n] = __builtin_amdgcn_mfma_f32_16x16x32_bf16(a[m], b[n],
                                                              acc[m][n], 0, 0, 0);
    }
    __syncthreads();
    cur ^= 1;
  }

#pragma unroll
  for (int n = 0; n < 4; ++n) {
    const int gcol = bn + wn * 64 + n * 16 + lrow;
    const float bv = BIAS_RELU ? bias[gcol] : 0.f;
#pragma unroll
    for (int m = 0; m < 4; ++m) {
      const int gmBase = bm + wm * 64 + m * 16 + lsel * 4;
#pragma unroll
      for (int j = 0; j < 4; ++j) {
        const int gm = gmBase + j;
        if (gm < N_NODES) {
          float v = acc[m][n][j] + bv;
          if (BIAS_RELU) v = fmaxf(v, 0.f);
          C[(size_t)gm * M + gcol] = f2b(v);
        }
      }
    }
  }
}

// ---------------------------------------------------------------------------
extern "C" void kernel_launch(void* const* d_in, const int* in_sizes, int n_in,
                              void* d_out, int out_size, void* d_ws,
                              size_t ws_size, hipStream_t stream) {
  const float* x   = (const float*)d_in[0];
  const int*   src = (const int*)d_in[1];
  const int*   dst = (const int*)d_in[2];
  const float* ew  = (const float*)d_in[3];
  const float* W1  = (const float*)d_in[4];
  const float* b1  = (const float*)d_in[5];
  const float* W2  = (const float*)d_in[6];
  const float* b2  = (const float*)d_in[7];
  const float* W3  = (const float*)d_in[8];
  const float* b3  = (const float*)d_in[9];

  // ws layout: two bf16 activation buffers (51.2 MB each) + CSR + Wb
  unsigned short* buf0 = (unsigned short*)d_ws;
  unsigned short* buf1 = buf0 + (size_t)N_NODES * 256;
  int* csr = (int*)((char*)d_ws + 102400000);           // 16B-aligned
  int*   start        = csr;                            // @0      (100001)
  int*   bucket_start = csr + 100004;                   // @100004 (392)
  int*   cursorA      = csr + 100400;                   // @100400 (391)
  uint2* edges        = (uint2*)(csr + 100800);         // 16B-aligned, 12.8MB
  unsigned short* Wb1 = (unsigned short*)(edges + N_EDGES);  // [256][128]
  unsigned short* Wb2 = Wb1 + 256 * 128;                     // [256][256]
  unsigned short* Wb3 = Wb2 + 256 * 256;                     // [128][256]
  // pass-A staging lives in buf1 (dead until layer-1 aggregate output)
  uint2* edgesA    = (uint2*)buf1;

  // ---- CSR build (bucket-level hist + tiny scan; node scan inside sort)
  zero_i32<<<2, 256, 0, stream>>>(bucket_start, NBUCK + 1);
  bucket_hist<<<SCAT_GRID, 256, 0, stream>>>(dst, bucket_start);
  scan_buckets<<<1, 512, 0, stream>>>(bucket_start, cursorA);
  bucket_scatter<<<SCAT_GRID, 256, 0, stream>>>(src, dst, ew, cursorA, edgesA);
  bucket_sort<<<NBUCK, 512, 0, stream>>>(edgesA, bucket_start, start, edges);

  // ---- weight prep (bf16, transposed) + xb = bf16(x)
  cvt_w_all<<<640, 128, 0, stream>>>(W1, W2, W3, Wb1, Wb2, Wb3);
  cvt_f32_bf16<<<(N_NODES * 128 / 8 + 255) / 256, 256, 0, stream>>>(
      (const float4*)x, (uint4*)buf0, N_NODES * 128 / 8);

  // ---- Layer 1: h1 = relu((A xb) W1 + b1)
  aggregate_k<128, false><<<6250, 256, 0, stream>>>(
      (const uint4*)buf0, start, edges, buf1, nullptr);
  gemm_mfma<128, 2, true><<<1564, 256, 0, stream>>>(buf1, Wb1, b1, buf0, 256);

  // ---- Layer 2: h2 = relu((A h1) W2 + b2)
  aggregate_k<256, false><<<12500, 256, 0, stream>>>(
      (const uint4*)buf0, start, edges, buf1, nullptr);
  gemm_mfma<256, 2, true><<<1564, 256, 0, stream>>>(buf1, Wb2, b2, buf0, 256);

  // ---- Layer 3: out = A (h2 W3) + b3   (aggregate at D=128, bias in epilogue)
  gemm_mfma<256, 1, false><<<782, 256, 0, stream>>>(buf0, Wb3, nullptr, buf1, 128);
  aggregate_k<128, true><<<6250, 256, 0, stream>>>(
      (const uint4*)buf1, start, edges, d_out, b3);
}